// Round 1
// baseline (84.937 us; speedup 1.0000x reference)
//
#include <hip/hip_runtime.h>
#include <hip/hip_bf16.h>

// ---------------------------------------------------------------------------
// Compile-time generation of the spectral transform matrices.
//
// Math: out = w .* mc + d * e0,  d = 0.5*log(S1/S2),
//   S = sum_k exp( sum_m CB[k][m]*mc[m] + lnw_k )   (CB folds the 2x and freqt+cos)
// where CB[k][m] = 2 * sum_l A_FT[l][m] * cos(2*pi*k*l/128),
//       CBW      = CB * cepstral_weight (1,1,1.2,...),
//       extra column m=25 holds ln(spectral bin weight) (0 for k=0,64 else ln2),
// because b2mc(mc2b(x)) == x exactly (inverse recurrences), so the 25x25
// matmuls collapse to identity.
// ---------------------------------------------------------------------------

namespace cg {

constexpr int L  = 128;   // IR length
constexpr int M1 = 25;    // cep order + 1
constexpr int NK = 65;    // rfft bins
constexpr int MP = 28;    // padded row length (16B-aligned rows)

struct CosTab { double v[L]; };
constexpr CosTab make_costab() {
    CosTab t{};
    const double PI = 3.14159265358979323846;
    for (int i = 0; i < L; ++i) {
        int j = (i <= 64) ? i : i - 128;          // reduce to [-pi, pi]
        double x = (2.0 * PI * (double)j) / 128.0;
        double x2 = x * x, term = 1.0, s = 1.0;
        for (int n = 1; n <= 16; ++n) {
            term *= -x2 / ((2.0 * n - 1.0) * (2.0 * n));
            s += term;
        }
        t.v[i] = s;
    }
    return t;
}
constexpr CosTab CT = make_costab();

struct AMat { double v[L][M1]; };
constexpr AMat make_aft() {
    AMat A{};                     // zero-init
    const double al = -0.42;      // alpha passed to freqt is -ALPHA
    double p = 1.0;
    for (int j = 0; j < M1; ++j) { A.v[0][j] = p; p *= al; }
    double q = 1.0;
    for (int j = 1; j < M1; ++j) { A.v[1][j] = q * (double)j * (1.0 - al * al); q *= al; }
    for (int i = 2; i < L; ++i)
        for (int j = 1; j < M1; ++j)
            A.v[i][j] = A.v[i - 1][j - 1] + al * (A.v[i][j - 1] - A.v[i - 1][j]);
    return A;
}
constexpr AMat AFT = make_aft();

// Chunked cosine transform (keeps each constexpr evaluation < step limit).
struct Chunk { double v[8][M1]; };
template <int K0>
constexpr Chunk make_chunk() {
    Chunk c{};
    for (int kk = 0; kk < 8; ++kk) {
        int k = K0 + kk;
        for (int m = 0; m < M1; ++m) {
            double s = 0.0;
            for (int l = 0; l < L; ++l)
                s += AFT.v[l][m] * CT.v[(k * l) & 127];
            c.v[kk][m] = s;
        }
    }
    return c;
}
constexpr Chunk CH0 = make_chunk<0>();
constexpr Chunk CH1 = make_chunk<8>();
constexpr Chunk CH2 = make_chunk<16>();
constexpr Chunk CH3 = make_chunk<24>();
constexpr Chunk CH4 = make_chunk<32>();
constexpr Chunk CH5 = make_chunk<40>();
constexpr Chunk CH6 = make_chunk<48>();
constexpr Chunk CH7 = make_chunk<56>();
constexpr Chunk CH8 = make_chunk<64>();

struct Pack { float cb[NK][MP]; float cbw[NK][MP]; };
constexpr Pack make_pack() {
    const Chunk* chs[9] = { &CH0, &CH1, &CH2, &CH3, &CH4, &CH5, &CH6, &CH7, &CH8 };
    Pack p{};  // zero-init (padding columns 26,27 = 0)
    const double LN2 = 0.69314718055994530942;
    for (int k = 0; k < NK; ++k) {
        const Chunk& c = *chs[k >> 3];
        double logw = (k == 0 || k == 64) ? 0.0 : LN2;
        for (int m = 0; m < M1; ++m) {
            double b  = 2.0 * c.v[k & 7][m];
            double cw = (m < 2) ? 1.0 : 1.2;       // 1 + BETA, ONSET = 2
            p.cb[k][m]  = (float)b;
            p.cbw[k][m] = (float)(b * cw);
        }
        p.cb[k][M1]  = (float)logw;                // ln(bin weight) column
        p.cbw[k][M1] = (float)logw;
    }
    return p;
}

} // namespace cg

__constant__ cg::Pack g_P = cg::make_pack();

// ---------------------------------------------------------------------------
// Kernel: one thread = one row of 25 mel-cepstra.
// ---------------------------------------------------------------------------

__global__ __launch_bounds__(256)
void mcpf_kernel(const float* __restrict__ mc, float* __restrict__ out) {
    __shared__ float sbuf[256 * 25];               // 25.6 KB
    const int tid = threadIdx.x;
    const long long base = (long long)blockIdx.x * (256LL * 25);

    // coalesced float4 stage-in (1600 float4 per block)
    const float4* __restrict__ src4 = reinterpret_cast<const float4*>(mc + base);
    float4* sb4 = reinterpret_cast<float4*>(sbuf);
#pragma unroll
    for (int i = 0; i < 7; ++i) {
        int idx = tid + i * 256;
        if (idx < 1600) sb4[idx] = src4[idx];
    }
    __syncthreads();

    // per-thread row (stride 25 words: odd stride -> <=2-way bank alias, free)
    float v[26];
#pragma unroll
    for (int m = 0; m < 25; ++m) v[m] = sbuf[tid * 25 + m];
    v[25] = 1.0f;                                  // constant column for ln(w_k)

    float S1 = 0.0f, S2 = 0.0f;
    for (int k = 0; k < 65; ++k) {
        float y1 = 0.0f, y2 = 0.0f;
#pragma unroll
        for (int m = 0; m < 26; ++m) {
            y1 = g_P.cb[k][m]  * v[m] + y1;        // s_load (uniform k) + v_fma
            y2 = g_P.cbw[k][m] * v[m] + y2;
        }
        S1 += __expf(y1);
        S2 += __expf(y2);
    }
    const float d = 0.5f * (__logf(S1) - __logf(S2));

    // write result row back into the same LDS region (only this thread read it)
    sbuf[tid * 25 + 0] = v[0] + d;                 // w[0] = 1
    sbuf[tid * 25 + 1] = v[1];                     // w[1] = 1
#pragma unroll
    for (int m = 2; m < 25; ++m) sbuf[tid * 25 + m] = 1.2f * v[m];
    __syncthreads();

    // coalesced float4 store-out
    float4* __restrict__ dst4 = reinterpret_cast<float4*>(out + base);
#pragma unroll
    for (int i = 0; i < 7; ++i) {
        int idx = tid + i * 256;
        if (idx < 1600) dst4[idx] = sb4[idx];
    }
}

extern "C" void kernel_launch(void* const* d_in, const int* in_sizes, int n_in,
                              void* d_out, int out_size, void* d_ws, size_t ws_size,
                              hipStream_t stream) {
    const float* mc = (const float*)d_in[0];
    float* out = (float*)d_out;
    const int rows = in_sizes[0] / 25;             // 16*32768 = 524288
    const int blocks = rows / 256;                 // 2048 (divides exactly)
    mcpf_kernel<<<dim3(blocks), dim3(256), 0, stream>>>(mc, out);
}

// Round 3
// 77.653 us; speedup vs baseline: 1.0938x; 1.0938x over previous
//
#include <hip/hip_runtime.h>
#include <hip/hip_bf16.h>

// ---------------------------------------------------------------------------
// out = w .* mc + d * e0,   d = 0.5*ln(S1/S2)
// S1 = sum_k 2^( a_k + t_k ),  S2 = sum_k 2^( a_k + 1.2*t_k )
//   a_k = C[k][0]*v0 + C[k][1]*v1 + lw_k
//   t_k = sum_{m=2..24} C[k][m]*v[m]
// C[k][m] = log2(e) * 2 * sum_l A_FT[l][m] * cos(2*pi*k*l/128)
// lw_k    = log2(spectral bin weight) = 0 for k=0,64 ; exactly 1.0 otherwise
// (b2mc∘mc2b == identity, so the 25x25 matmuls collapse; verified round 1.)
// ---------------------------------------------------------------------------

namespace cg {

constexpr int L  = 128;
constexpr int M1 = 25;
constexpr int NK = 65;
constexpr int MP = 28;    // padded row: [0..24]=C, [25]=lw, [26,27]=0

struct CosTab { double v[L]; };
constexpr CosTab make_costab() {
    CosTab t{};
    const double PI = 3.14159265358979323846;
    for (int i = 0; i < L; ++i) {
        int j = (i <= 64) ? i : i - 128;
        double x = (2.0 * PI * (double)j) / 128.0;
        double x2 = x * x, term = 1.0, s = 1.0;
        for (int n = 1; n <= 16; ++n) {
            term *= -x2 / ((2.0 * n - 1.0) * (2.0 * n));
            s += term;
        }
        t.v[i] = s;
    }
    return t;
}
constexpr CosTab CT = make_costab();

struct AMat { double v[L][M1]; };
constexpr AMat make_aft() {
    AMat A{};
    const double al = -0.42;          // freqt called with -ALPHA
    double p = 1.0;
    for (int j = 0; j < M1; ++j) { A.v[0][j] = p; p *= al; }
    double q = 1.0;
    for (int j = 1; j < M1; ++j) { A.v[1][j] = q * (double)j * (1.0 - al * al); q *= al; }
    for (int i = 2; i < L; ++i)
        for (int j = 1; j < M1; ++j)
            A.v[i][j] = A.v[i - 1][j - 1] + al * (A.v[i][j - 1] - A.v[i - 1][j]);
    return A;
}
constexpr AMat AFT = make_aft();

struct Chunk { double v[8][M1]; };
template <int K0>
constexpr Chunk make_chunk() {
    Chunk c{};
    for (int kk = 0; kk < 8; ++kk) {
        int k = K0 + kk;
        for (int m = 0; m < M1; ++m) {
            double s = 0.0;
            for (int l = 0; l < L; ++l)
                s += AFT.v[l][m] * CT.v[(k * l) & 127];
            c.v[kk][m] = s;
        }
    }
    return c;
}
constexpr Chunk CH0 = make_chunk<0>();
constexpr Chunk CH1 = make_chunk<8>();
constexpr Chunk CH2 = make_chunk<16>();
constexpr Chunk CH3 = make_chunk<24>();
constexpr Chunk CH4 = make_chunk<32>();
constexpr Chunk CH5 = make_chunk<40>();
constexpr Chunk CH6 = make_chunk<48>();
constexpr Chunk CH7 = make_chunk<56>();
constexpr Chunk CH8 = make_chunk<64>();

struct Pack { float c[NK][MP]; };
constexpr Pack make_pack() {
    const Chunk* chs[9] = { &CH0, &CH1, &CH2, &CH3, &CH4, &CH5, &CH6, &CH7, &CH8 };
    Pack p{};
    const double LOG2E = 1.44269504088896340736;
    for (int k = 0; k < NK; ++k) {
        const Chunk& c = *chs[k >> 3];
        for (int m = 0; m < M1; ++m)
            p.c[k][m] = (float)(LOG2E * 2.0 * c.v[k & 7][m]);
        p.c[k][M1] = (k == 0 || k == 64) ? 0.0f : 1.0f;   // log2(bin weight)
    }
    return p;
}

} // namespace cg

__constant__ cg::Pack g_P = cg::make_pack();

// ---------------------------------------------------------------------------
// One thread = one row of 25 mel-cepstra.
// ---------------------------------------------------------------------------

__global__ __launch_bounds__(256)
void mcpf_kernel(const float* __restrict__ mc, float* __restrict__ out) {
    __shared__ float sbuf[256 * 25];               // 25.6 KB
    const int tid = threadIdx.x;
    const long long base = (long long)blockIdx.x * (256LL * 25);

    // coalesced float4 stage-in (1600 float4 per block)
    const float4* __restrict__ src4 = reinterpret_cast<const float4*>(mc + base);
    float4* sb4 = reinterpret_cast<float4*>(sbuf);
#pragma unroll
    for (int i = 0; i < 7; ++i) {
        int idx = tid + i * 256;
        if (idx < 1600) sb4[idx] = src4[idx];
    }
    __syncthreads();

    float v[25];
#pragma unroll
    for (int m = 0; m < 25; ++m) v[m] = sbuf[tid * 25 + m];

    const float* __restrict__ C = &g_P.c[0][0];

    float S1 = 0.0f, S2 = 0.0f;
#pragma clang loop unroll_count(2)
    for (int k = 0; k < 65; ++k) {
        const float* __restrict__ r = C + k * cg::MP;   // runtime k -> s_load
        // a = C0*v0 + C1*v1 + lw
        float a = __builtin_fmaf(r[0], v[0], __builtin_fmaf(r[1], v[1], r[25]));
        // t = sum_{m=2..24} C[m]*v[m], two chains
        float ta = 0.0f, tb = 0.0f;
#pragma unroll
        for (int m = 2; m < 24; m += 2) {
            ta = __builtin_fmaf(r[m],     v[m],     ta);
            tb = __builtin_fmaf(r[m + 1], v[m + 1], tb);
        }
        ta = __builtin_fmaf(r[24], v[24], ta);
        const float t  = ta + tb;
        const float y1 = a + t;
        const float y2 = __builtin_fmaf(0.2f, t, y1);   // a + 1.2*t
        S1 += __builtin_amdgcn_exp2f(y1);
        S2 += __builtin_amdgcn_exp2f(y2);
    }
    // d = 0.5*ln(S1/S2) = 0.5*ln2*(log2 S1 - log2 S2)
    const float d = 0.34657359027997264f *
                    (__builtin_amdgcn_logf(S1) - __builtin_amdgcn_logf(S2));

    // write result row back into LDS (only this thread read this region)
    sbuf[tid * 25 + 0] = v[0] + d;                 // w[0] = 1
    sbuf[tid * 25 + 1] = v[1];                     // w[1] = 1
#pragma unroll
    for (int m = 2; m < 25; ++m) sbuf[tid * 25 + m] = 1.2f * v[m];
    __syncthreads();

    // coalesced float4 store-out
    float4* __restrict__ dst4 = reinterpret_cast<float4*>(out + base);
#pragma unroll
    for (int i = 0; i < 7; ++i) {
        int idx = tid + i * 256;
        if (idx < 1600) dst4[idx] = sb4[idx];
    }
}

extern "C" void kernel_launch(void* const* d_in, const int* in_sizes, int n_in,
                              void* d_out, int out_size, void* d_ws, size_t ws_size,
                              hipStream_t stream) {
    const float* mc = (const float*)d_in[0];
    float* out = (float*)d_out;
    const int rows = in_sizes[0] / 25;             // 524288
    const int blocks = rows / 256;                 // 2048
    mcpf_kernel<<<dim3(blocks), dim3(256), 0, stream>>>(mc, out);
}

// Round 4
// 32.273 us; speedup vs baseline: 2.6318x; 2.4061x over previous
//
#include <hip/hip_runtime.h>

// ---------------------------------------------------------------------------
// out = w .* mc + d * e0,   d = 0.5*ln(S1/S2) = 0.5*ln2*(log2 S1 - log2 S2)
// y[row][col] = sum_k A[row][k] * B[k][col]   (MFMA 16x16x32 f16, K=32, N=144)
//   A[row][0..24] = mc row, A[row][25] = 1.0, rest 0
//   B[k<25][col<65]    = C[col][k]          (log2-domain freqt+cos matrix)
//   B[k<25][65<=c<130] = C[c-65][k]*w[k]    (w = 1,1,1.2,1.2,... ONSET=2)
//   B[25][col]         = log2(bin weight): 0 for bin 0,64; 1 else; -1e4 for pad
// S1 = sum over cols 0..64 of 2^y, S2 = cols 65..129.  (b2mc∘mc2b == I.)
// ---------------------------------------------------------------------------

namespace cg {

constexpr int L  = 128;
constexpr int M1 = 25;

struct CosTab { double v[L]; };
constexpr CosTab make_costab() {
    CosTab t{};
    const double PI = 3.14159265358979323846;
    for (int i = 0; i < L; ++i) {
        int j = (i <= 64) ? i : i - 128;
        double x = (2.0 * PI * (double)j) / 128.0;
        double x2 = x * x, term = 1.0, s = 1.0;
        for (int n = 1; n <= 16; ++n) {
            term *= -x2 / ((2.0 * n - 1.0) * (2.0 * n));
            s += term;
        }
        t.v[i] = s;
    }
    return t;
}
constexpr CosTab CT = make_costab();

struct AMat { double v[L][M1]; };
constexpr AMat make_aft() {
    AMat A{};
    const double al = -0.42;          // freqt called with -ALPHA
    double p = 1.0;
    for (int j = 0; j < M1; ++j) { A.v[0][j] = p; p *= al; }
    double q = 1.0;
    for (int j = 1; j < M1; ++j) { A.v[1][j] = q * (double)j * (1.0 - al * al); q *= al; }
    for (int i = 2; i < L; ++i)
        for (int j = 1; j < M1; ++j)
            A.v[i][j] = A.v[i - 1][j - 1] + al * (A.v[i][j - 1] - A.v[i - 1][j]);
    return A;
}
constexpr AMat AFT = make_aft();

struct Chunk { double v[8][M1]; };
template <int K0>
constexpr Chunk make_chunk() {
    Chunk c{};
    for (int kk = 0; kk < 8; ++kk) {
        int k = K0 + kk;
        for (int m = 0; m < M1; ++m) {
            double s = 0.0;
            for (int l = 0; l < L; ++l)
                s += AFT.v[l][m] * CT.v[(k * l) & 127];
            c.v[kk][m] = s;
        }
    }
    return c;
}
constexpr Chunk CH0 = make_chunk<0>();
constexpr Chunk CH1 = make_chunk<8>();
constexpr Chunk CH2 = make_chunk<16>();
constexpr Chunk CH3 = make_chunk<24>();
constexpr Chunk CH4 = make_chunk<32>();
constexpr Chunk CH5 = make_chunk<40>();
constexpr Chunk CH6 = make_chunk<48>();
constexpr Chunk CH7 = make_chunk<56>();
constexpr Chunk CH8 = make_chunk<64>();

constexpr double chunkval(int bin, int m) {
    const Chunk* chs[9] = { &CH0, &CH1, &CH2, &CH3, &CH4, &CH5, &CH6, &CH7, &CH8 };
    return chs[bin >> 3]->v[bin & 7][m];
}

// Logical B[k][col] in log2 domain (fragment layout applied in make_bf).
constexpr float blogical(int k, int col) {
    const double LOG2E = 1.44269504088896340736;
    if (col >= 130) return (k == 25) ? -1.0e4f : 0.0f;   // pad cols: exp2 -> 0
    int bin = (col < 65) ? col : (col - 65);
    if (k == 25) return (bin == 0 || bin == 64) ? 0.0f : 1.0f;  // log2(bin wt)
    if (k > 25) return 0.0f;
    double c = LOG2E * 2.0 * chunkval(bin, k);
    if (col >= 65 && k >= 2) c *= 1.2;                   // cepstral weight
    return (float)c;
}

// B pre-swizzled into MFMA fragment order: v[tile][lane][j],
// lane l holds B[k=(l>>4)*8+j][col=tile*16+(l&15)].
struct BF { alignas(16) float v[9][64][8]; };
constexpr BF make_bf() {
    BF b{};
    for (int n = 0; n < 9; ++n)
        for (int l = 0; l < 64; ++l)
            for (int j = 0; j < 8; ++j)
                b.v[n][l][j] = blogical((l >> 4) * 8 + j, n * 16 + (l & 15));
    return b;
}

} // namespace cg

__device__ const cg::BF g_Bf = cg::make_bf();

typedef _Float16 f16x8 __attribute__((ext_vector_type(8)));
typedef float    f32x4 __attribute__((ext_vector_type(4)));

// ---------------------------------------------------------------------------
// 256 threads = 4 waves; block handles 256 rows. Wave w: rows [w*64, w*64+64)
// as 4 groups of 16 rows (one A-frag each).
// ---------------------------------------------------------------------------
__global__ __launch_bounds__(256)
void mcpf_kernel(const float* __restrict__ mc, float* __restrict__ out) {
    __shared__ __align__(16) float sbuf[256 * 25 + 8];   // +pad for masked reads
    __shared__ float d_lds[256];
    const int tid = threadIdx.x;
    const long long base = (long long)blockIdx.x * (256LL * 25);

    // coalesced float4 stage-in
    const float4* __restrict__ src4 = reinterpret_cast<const float4*>(mc + base);
    float4* sb4 = reinterpret_cast<float4*>(sbuf);
#pragma unroll
    for (int i = 0; i < 7; ++i) {
        int idx = tid + i * 256;
        if (idx < 1600) sb4[idx] = src4[idx];
    }

    // B fragments: one-time per-wave load into VGPRs (L2/L3-resident rodata)
    const int lane = tid & 63;
    const int wv   = tid >> 6;
    const int r0   = lane & 15;     // fragment row / output col index
    const int kg   = lane >> 4;     // K group 0..3
    f16x8 bfrag[9];
#pragma unroll
    for (int n = 0; n < 9; ++n) {
        const float* p = &g_Bf.v[n][lane][0];
        float4 f0 = *reinterpret_cast<const float4*>(p);
        float4 f1 = *reinterpret_cast<const float4*>(p + 4);
        f16x8 t;
        t[0] = (_Float16)f0.x; t[1] = (_Float16)f0.y;
        t[2] = (_Float16)f0.z; t[3] = (_Float16)f0.w;
        t[4] = (_Float16)f1.x; t[5] = (_Float16)f1.y;
        t[6] = (_Float16)f1.z; t[7] = (_Float16)f1.w;
        bfrag[n] = t;
    }

    __syncthreads();

#pragma unroll
    for (int g = 0; g < 4; ++g) {
        const int rowbase = wv * 64 + g * 16;
        const float* __restrict__ arow = &sbuf[(rowbase + r0) * 25];

        // A fragment: lane holds row r0, k = kg*8 + j
        f16x8 af;
        if (kg < 3) {
#pragma unroll
            for (int j = 0; j < 8; ++j) af[j] = (_Float16)arow[kg * 8 + j];
        } else {
            af[0] = (_Float16)arow[24];      // k=24
            af[1] = (_Float16)1.0f;          // k=25: constant column for lw
#pragma unroll
            for (int j = 2; j < 8; ++j) af[j] = (_Float16)0.0f;
        }

        float s1[4] = {0.f, 0.f, 0.f, 0.f};
        float s2[4] = {0.f, 0.f, 0.f, 0.f};
#pragma unroll
        for (int n = 0; n < 9; ++n) {
            f32x4 acc = {0.f, 0.f, 0.f, 0.f};
            acc = __builtin_amdgcn_mfma_f32_16x16x32_f16(af, bfrag[n], acc, 0, 0, 0);
#pragma unroll
            for (int j = 0; j < 4; ++j) {
                float e = __builtin_amdgcn_exp2f(acc[j]);
                if (n < 4) {
                    s1[j] += e;                        // cols 0..63: S1
                } else if (n == 4) {                   // cols 64..79: mixed
                    bool c = (r0 == 0);                // col 64 -> S1
                    s1[j] += c ? e : 0.0f;
                    s2[j] += c ? 0.0f : e;
                } else {
                    s2[j] += e;                        // cols 80..143 (pad->0)
                }
            }
        }

        // reduce across the 16 columns (lanes r0=0..15 within kg subgroup)
#pragma unroll
        for (int j = 0; j < 4; ++j) {
#pragma unroll
            for (int msk = 1; msk < 16; msk <<= 1) {
                s1[j] += __shfl_xor(s1[j], msk);
                s2[j] += __shfl_xor(s2[j], msk);
            }
        }

        if (r0 == 0) {
#pragma unroll
            for (int j = 0; j < 4; ++j) {
                float d = 0.34657359027997264f *
                          (__builtin_amdgcn_logf(s1[j]) - __builtin_amdgcn_logf(s2[j]));
                d_lds[rowbase + kg * 4 + j] = d;       // row = kg*4 + j
            }
        }
    }

    __syncthreads();

    // postfilter scale + energy compensation, in place (own row only)
    {
        const float d = d_lds[tid];
        float* __restrict__ row = &sbuf[tid * 25];
        float o0 = row[0] + d;                          // w[0]=1, +d on elem 0
        float o1 = row[1];                              // w[1]=1
        float o[23];
#pragma unroll
        for (int m = 2; m < 25; ++m) o[m - 2] = 1.2f * row[m];
        row[0] = o0; row[1] = o1;
#pragma unroll
        for (int m = 2; m < 25; ++m) row[m] = o[m - 2];
    }
    __syncthreads();

    // coalesced float4 store-out
    float4* __restrict__ dst4 = reinterpret_cast<float4*>(out + base);
#pragma unroll
    for (int i = 0; i < 7; ++i) {
        int idx = tid + i * 256;
        if (idx < 1600) dst4[idx] = sb4[idx];
    }
}

extern "C" void kernel_launch(void* const* d_in, const int* in_sizes, int n_in,
                              void* d_out, int out_size, void* d_ws, size_t ws_size,
                              hipStream_t stream) {
    const float* mc = (const float*)d_in[0];
    float* out = (float*)d_out;
    const int rows = in_sizes[0] / 25;             // 524288
    const int blocks = rows / 256;                 // 2048
    mcpf_kernel<<<dim3(blocks), dim3(256), 0, stream>>>(mc, out);
}

// Round 5
// 27.632 us; speedup vs baseline: 3.0738x; 1.1680x over previous
//
#include <hip/hip_runtime.h>

// ---------------------------------------------------------------------------
// out = w .* mc + d * e0,   d = 0.5*ln(S1/S2) = 0.5*ln2*(log2 S1 - log2 S2)
// Swapped MFMA (16x16x32 f16):  D = Bmat^T * mc^T, so each lane's C/D regs
// hold 4 spectral cols of ONE mc-row -> column reduce is in-lane + 2 shfls.
//   A-op[i=col][k] = Bmat[k][col] ;  B-op[k][j=row] = mc[row][k]
//   Bmat[k<25][col<65]   = C[col][k]        (log2-domain freqt+cos)
//   Bmat[k<25][65<=c<130]= C[c-65][k]*w[k]  (w = 1,1,1.2,... ONSET=2)
//   Bmat[25][col]        = log2(bin wt): 0 bins 0,64; 1 else; -1e4 pads
// S1 = cols 0..64, S2 = cols 65..129, pads 130..143 -> exp2(-1e4)=0.
// (b2mc∘mc2b == I, so the 25x25 matmuls collapse; verified round 1/4.)
// ---------------------------------------------------------------------------

namespace cg {

constexpr int L  = 128;
constexpr int M1 = 25;

struct CosTab { double v[L]; };
constexpr CosTab make_costab() {
    CosTab t{};
    const double PI = 3.14159265358979323846;
    for (int i = 0; i < L; ++i) {
        int j = (i <= 64) ? i : i - 128;
        double x = (2.0 * PI * (double)j) / 128.0;
        double x2 = x * x, term = 1.0, s = 1.0;
        for (int n = 1; n <= 16; ++n) {
            term *= -x2 / ((2.0 * n - 1.0) * (2.0 * n));
            s += term;
        }
        t.v[i] = s;
    }
    return t;
}
constexpr CosTab CT = make_costab();

struct AMat { double v[L][M1]; };
constexpr AMat make_aft() {
    AMat A{};
    const double al = -0.42;          // freqt called with -ALPHA
    double p = 1.0;
    for (int j = 0; j < M1; ++j) { A.v[0][j] = p; p *= al; }
    double q = 1.0;
    for (int j = 1; j < M1; ++j) { A.v[1][j] = q * (double)j * (1.0 - al * al); q *= al; }
    for (int i = 2; i < L; ++i)
        for (int j = 1; j < M1; ++j)
            A.v[i][j] = A.v[i - 1][j - 1] + al * (A.v[i][j - 1] - A.v[i - 1][j]);
    return A;
}
constexpr AMat AFT = make_aft();

struct Chunk { double v[8][M1]; };
template <int K0>
constexpr Chunk make_chunk() {
    Chunk c{};
    for (int kk = 0; kk < 8; ++kk) {
        int k = K0 + kk;
        for (int m = 0; m < M1; ++m) {
            double s = 0.0;
            for (int l = 0; l < L; ++l)
                s += AFT.v[l][m] * CT.v[(k * l) & 127];
            c.v[kk][m] = s;
        }
    }
    return c;
}
constexpr Chunk CH0 = make_chunk<0>();
constexpr Chunk CH1 = make_chunk<8>();
constexpr Chunk CH2 = make_chunk<16>();
constexpr Chunk CH3 = make_chunk<24>();
constexpr Chunk CH4 = make_chunk<32>();
constexpr Chunk CH5 = make_chunk<40>();
constexpr Chunk CH6 = make_chunk<48>();
constexpr Chunk CH7 = make_chunk<56>();
constexpr Chunk CH8 = make_chunk<64>();

constexpr double chunkval(int bin, int m) {
    const Chunk* chs[9] = { &CH0, &CH1, &CH2, &CH3, &CH4, &CH5, &CH6, &CH7, &CH8 };
    return chs[bin >> 3]->v[bin & 7][m];
}

constexpr double blogical(int k, int col) {
    const double LOG2E = 1.44269504088896340736;
    if (col >= 130) return (k == 25) ? -1.0e4 : 0.0;     // pad cols: exp2 -> 0
    int bin = (col < 65) ? col : (col - 65);
    if (k == 25) return (bin == 0 || bin == 64) ? 0.0 : 1.0;  // log2(bin wt)
    if (k > 25) return 0.0;
    double c = LOG2E * 2.0 * chunkval(bin, k);
    if (col >= 65 && k >= 2) c *= 1.2;                   // cepstral weight
    return c;
}

// constexpr float->half (RN-ish; accuracy far beyond what we need)
constexpr unsigned short f2h(double v) {
    if (v == 0.0) return 0;
    unsigned short s = 0;
    if (v < 0) { s = 0x8000; v = -v; }
    int e = 0;
    while (v >= 2.0) { v *= 0.5; ++e; }
    while (v < 1.0)  { v *= 2.0; --e; }
    if (e > 15) return (unsigned short)(s | 0x7c00);
    if (e < -14) return s;                               // flush tiny to 0
    int mant = (int)((v - 1.0) * 1024.0 + 0.5);
    if (mant == 1024) { mant = 0; ++e; if (e > 15) return (unsigned short)(s | 0x7c00); }
    return (unsigned short)(s | ((e + 15) << 10) | mant);
}

// A-operand fragment per tile: lane l, reg j holds A[i=l&15][k=(l>>4)*8+j]
//   = Bmat[(l>>4)*8+j][N*16 + (l&15)]
struct Tile { unsigned short v[64][8]; };
template <int N>
constexpr Tile make_tile() {
    Tile t{};
    for (int l = 0; l < 64; ++l)
        for (int j = 0; j < 8; ++j)
            t.v[l][j] = f2h(blogical((l >> 4) * 8 + j, N * 16 + (l & 15)));
    return t;
}
constexpr Tile T0 = make_tile<0>();
constexpr Tile T1 = make_tile<1>();
constexpr Tile T2 = make_tile<2>();
constexpr Tile T3 = make_tile<3>();
constexpr Tile T4 = make_tile<4>();
constexpr Tile T5 = make_tile<5>();
constexpr Tile T6 = make_tile<6>();
constexpr Tile T7 = make_tile<7>();
constexpr Tile T8 = make_tile<8>();

struct BH { alignas(16) unsigned short v[9][64][8]; };
constexpr BH make_bh() {
    BH b{};
    const Tile* ts[9] = { &T0, &T1, &T2, &T3, &T4, &T5, &T6, &T7, &T8 };
    for (int n = 0; n < 9; ++n)
        for (int l = 0; l < 64; ++l)
            for (int j = 0; j < 8; ++j)
                b.v[n][l][j] = ts[n]->v[l][j];
    return b;
}

} // namespace cg

__device__ const cg::BH g_Bh = cg::make_bh();

typedef _Float16 f16x8 __attribute__((ext_vector_type(8)));
typedef float    f32x4 __attribute__((ext_vector_type(4)));

// ---------------------------------------------------------------------------
// 256 threads = 4 waves; block = 256 rows. Wave wv: rows [wv*64, wv*64+64)
// as 4 groups of 16 rows.
// ---------------------------------------------------------------------------
__global__ __launch_bounds__(256)
void mcpf_kernel(const float* __restrict__ mc, float* __restrict__ out) {
    __shared__ __align__(16) float sbuf[256 * 25 + 8];
    __shared__ float d_lds[272];                   // 256 used (+ OOB-safe pad)
    const int tid = threadIdx.x;
    const long long base = (long long)blockIdx.x * (256LL * 25);

    // coalesced float4 stage-in
    const float4* __restrict__ src4 = reinterpret_cast<const float4*>(mc + base);
    float4* sb4 = reinterpret_cast<float4*>(sbuf);
#pragma unroll
    for (int i = 0; i < 7; ++i) {
        int idx = tid + i * 256;
        if (idx < 1600) sb4[idx] = src4[idx];
    }

    // B-matrix fragments, pre-swizzled + pre-converted: 9x 16B loads
    const int lane = tid & 63;
    const int wv   = tid >> 6;
    const int r0   = lane & 15;     // mc-row within 16-group
    const int kg   = lane >> 4;     // K group 0..3 (also col subgroup in D)
    f16x8 bfrag[9];
#pragma unroll
    for (int n = 0; n < 9; ++n)
        bfrag[n] = *reinterpret_cast<const f16x8*>(&g_Bh.v[n][lane][0]);

    __syncthreads();

#pragma unroll
    for (int g = 0; g < 4; ++g) {
        const int rowbase = wv * 64 + g * 16;
        const float* __restrict__ arow = &sbuf[(rowbase + r0) * 25];

        // data fragment (B-operand): lane holds row r0, k = kg*8 + j
        f16x8 af;
        if (kg < 3) {
#pragma unroll
            for (int j = 0; j < 8; ++j) af[j] = (_Float16)arow[kg * 8 + j];
        } else {
            af[0] = (_Float16)arow[24];      // k=24
            af[1] = (_Float16)1.0f;          // k=25: constant column for lw
#pragma unroll
            for (int j = 2; j < 8; ++j) af[j] = (_Float16)0.0f;
        }

        // D[col][row]: this lane gets row r0, cols n*16 + kg*4 + r
        float s1 = 0.0f, s2 = 0.0f;
#pragma unroll
        for (int n = 0; n < 9; ++n) {
            f32x4 acc = {0.f, 0.f, 0.f, 0.f};
            acc = __builtin_amdgcn_mfma_f32_16x16x32_f16(bfrag[n], af, acc, 0, 0, 0);
#pragma unroll
            for (int r = 0; r < 4; ++r) {
                float e = __builtin_amdgcn_exp2f(acc[r]);
                if (n < 4) {
                    s1 += e;                           // cols 0..63
                } else if (n == 4 && r == 0) {
                    bool c = (kg == 0);                // col 64 -> S1
                    s1 += c ? e : 0.0f;
                    s2 += c ? 0.0f : e;
                } else {
                    s2 += e;                           // cols 65..143 (pads->0)
                }
            }
        }

        // cross-kg reduce: lanes r0 + 16*kg -> butterfly over bits 4,5
        s1 += __shfl_xor(s1, 16);
        s1 += __shfl_xor(s1, 32);
        s2 += __shfl_xor(s2, 16);
        s2 += __shfl_xor(s2, 32);

        if (kg == 0) {
            float d = 0.34657359027997264f *
                      (__builtin_amdgcn_logf(s1) - __builtin_amdgcn_logf(s2));
            d_lds[rowbase + r0] = d;
        }
    }

    __syncthreads();

    // fused store-out: out = w .* mc + d on element 0 of each row
    float4* __restrict__ dst4 = reinterpret_cast<float4*>(out + base);
#pragma unroll
    for (int i = 0; i < 7; ++i) {
        int idx = tid + i * 256;
        if (idx < 1600) {
            float4 v = sb4[idx];
            int f = idx * 4;
            int q = f / 25;
            int r = f - 25 * q;
            float dv0 = d_lds[q];
            float dv1 = d_lds[q + 1];              // in-bounds (<=256, padded)
            // w per component: 1 for cepstral index 0,1 else 1.2
            v.x *= (r     < 2)              ? 1.0f : 1.2f;
            v.y *= (r + 1 < 2 || r + 1 == 25) ? 1.0f : 1.2f;
            v.z *= (r + 2 == 25 || r + 2 == 26) ? 1.0f : 1.2f;
            v.w *= (r + 3 == 25 || r + 3 == 26) ? 1.0f : 1.2f;
            // +d on cepstral index 0 (w=1 there)
            if (r == 0)  v.x += dv0;
            if (r == 22) v.w += dv1;
            if (r == 23) v.z += dv1;
            if (r == 24) v.y += dv1;
            dst4[idx] = v;
        }
    }
}

extern "C" void kernel_launch(void* const* d_in, const int* in_sizes, int n_in,
                              void* d_out, int out_size, void* d_ws, size_t ws_size,
                              hipStream_t stream) {
    const float* mc = (const float*)d_in[0];
    float* out = (float*)d_out;
    const int rows = in_sizes[0] / 25;             // 524288
    const int blocks = rows / 256;                 // 2048
    mcpf_kernel<<<dim3(blocks), dim3(256), 0, stream>>>(mc, out);
}